// Round 1
// baseline (739.525 us; speedup 1.0000x reference)
//
#include <hip/hip_runtime.h>
#include <math.h>

// CRF forward partition scan. B=512, S=1024, T=48.
//
// R11: ILP via chain pairing. rocprof R10: VALUBusy 14.3%, HBM 1.4%,
// occupancy 5.7% -> latency-bound, one wave per SIMD on half the SIMDs,
// ~750 cyc/step dep-stall exposed. Fix: one wave now runs TWO independent
// batch chains (bA=2*blk, bB=2*blk+1), phases interleaved so chain B's
// issue fills chain A's stalls. 256 blocks (1/CU).
//  - mask gate is pair-any (skip only when BOTH chains masked off, ~9% of
//    steps); per-chain update via uniform cndmask. Per-chain branches would
//    serialize the chains' stall windows (in-order issue).
//  - T column now lives in 12 float4 REGISTERS (shared by both chains);
//    kills the per-step LOADT (12 ds_read_b128) that the fences forced to
//    re-issue. EV = exp(T) in 24 v2 regs as before (shared).
//  - LDS down to 4x64 floats (p_sh / ea_sh per chain).

constexpr int kB  = 512;
constexpr int kS  = 1024;
constexpr int kT  = 48;

typedef float v2 __attribute__((ext_vector_type(2)));
struct V2P { v2 lo, hi; };

#define REP12(X) X(0) X(1) X(2) X(3) X(4) X(5) X(6) X(7) X(8) X(9) X(10) X(11)

// X(k, i0, i1): EV pair k covers transition rows i0=2k, i1=2k+1
#define REP24(X) \
  X(0,0,1)    X(1,2,3)    X(2,4,5)    X(3,6,7) \
  X(4,8,9)    X(5,10,11)  X(6,12,13)  X(7,14,15) \
  X(8,16,17)  X(9,18,19)  X(10,20,21) X(11,22,23) \
  X(12,24,25) X(13,26,27) X(14,28,29) X(15,30,31) \
  X(16,32,33) X(17,34,35) X(18,36,37) X(19,38,39) \
  X(20,40,41) X(21,42,43) X(22,44,45) X(23,46,47)

// X(q, evA, evB, a, b): quad q (rows 4q..4q+3), EV pair ids, acc ids
#define REPQ(X) \
  X(0,0,1,0,3)    X(1,2,3,1,2)    X(2,4,5,2,1)    X(3,6,7,3,0) \
  X(4,8,9,0,3)    X(5,10,11,1,2)  X(6,12,13,2,1)  X(7,14,15,3,0) \
  X(8,16,17,0,3)  X(9,18,19,1,2)  X(10,20,21,2,1) X(11,22,23,3,0)

// Transition column j, rows 4q..4q+3, held in registers for the whole kernel.
#define DECL_TQ(q)  float4 TQ##q;
#define INIT_TQ(q)  { TQ##q.x = trans[(4*(q)+0)*kT + j]; \
                      TQ##q.y = trans[(4*(q)+1)*kT + j]; \
                      TQ##q.z = trans[(4*(q)+2)*kT + j]; \
                      TQ##q.w = trans[(4*(q)+3)*kT + j]; }

#define DECL_EV(k,i0,i1)  v2 EV##k;
#define INIT_EV(k,i0,i1)  EV##k = (v2){__expf(trans[(i0)*kT + j]), \
                                       __expf(trans[(i1)*kT + j])};

#define LOADP2(q)  const float4 PA##q = pA4[q]; const float4 PB##q = pB4[q];
#define LOADQ2(q)  const float4 QA##q = qA4[q]; const float4 QB##q = qB4[q];

// pass 1, both chains: mv[a] = max(mv[a], T.lo + p.lo); mv[b] likewise .hi
#define PASS1(q,evA,evB,a,b) { \
    const V2P t_  = __builtin_bit_cast(V2P, TQ##q); \
    const V2P pa_ = __builtin_bit_cast(V2P, PA##q); \
    const V2P pb_ = __builtin_bit_cast(V2P, PB##q); \
    mva##a = __builtin_elementwise_max(mva##a, t_.lo + pa_.lo); \
    mva##b = __builtin_elementwise_max(mva##b, t_.hi + pa_.hi); \
    mvb##a = __builtin_elementwise_max(mvb##a, t_.lo + pb_.lo); \
    mvb##b = __builtin_elementwise_max(mvb##b, t_.hi + pb_.hi); }

// pass 2, both chains: sv[a] += EV[evA] * q.lo; sv[b] += EV[evB] * q.hi
#define PASS2(q,evA,evB,a,b) { \
    const V2P qa_ = __builtin_bit_cast(V2P, QA##q); \
    const V2P qb_ = __builtin_bit_cast(V2P, QB##q); \
    sva##a = __builtin_elementwise_fma(EV##evA, qa_.lo, sva##a); \
    sva##b = __builtin_elementwise_fma(EV##evB, qa_.hi, sva##b); \
    svb##a = __builtin_elementwise_fma(EV##evA, qb_.lo, svb##a); \
    svb##b = __builtin_elementwise_fma(EV##evB, qb_.hi, svb##b); }

// Single-wave workgroup: LDS pipe is in-order per wave, so cross-lane RAW
// through LDS needs only a compiler scheduling fence, not s_barrier.
__device__ __forceinline__ void wave_fence() {
    __builtin_amdgcn_wave_barrier();
}

__global__ __launch_bounds__(64, 1) void crf_fwd(
    const float* __restrict__ feats,   // [B, S, T] fp32
    const int*   __restrict__ mask,    // [B, S] int32 (bool)
    const float* __restrict__ trans,   // [T, T] fp32
    float*       __restrict__ out)     // [1 + B]; we write out[1+b]
{
    const int pair = blockIdx.x;       // 256 blocks, 2 chains each
    const int bA   = 2 * pair;
    const int bB   = 2 * pair + 1;
    const int lane = threadIdx.x;
    const int j    = (lane < kT) ? lane : (kT - 1);  // clamp idle lanes

    __shared__ alignas(16) float p_shA[64];
    __shared__ alignas(16) float p_shB[64];
    __shared__ alignas(16) float ea_shA[64];
    __shared__ alignas(16) float ea_shB[64];
    const float4* pA4 = (const float4*)p_shA;
    const float4* pB4 = (const float4*)p_shB;
    const float4* qA4 = (const float4*)ea_shA;
    const float4* qB4 = (const float4*)ea_shB;

    // T column in regs (shared A/B), E column as 24 packed float2 in regs.
    REP12(DECL_TQ)
    REP12(INIT_TQ)
    REP24(DECL_EV)
    REP24(INIT_EV)

    const float* fbA = feats + (size_t)bA * kS * kT + j;
    const float* fbB = feats + (size_t)bB * kS * kT + j;
    const int*   mbA = mask  + (size_t)bA * kS;
    const int*   mbB = mask  + (size_t)bB * kS;

    // part0 = emit[0] + transition[T-2, :]   (row 46, column j)
    float partA = fbA[0] + trans[(kT - 2) * kT + j];
    float partB = fbB[0] + trans[(kT - 2) * kT + j];
    p_shA[lane] = partA;
    p_shB[lane] = partB;
    wave_fence();   // order init p_sh writes before loop reads

    // Depth-4 register-rotated emission prefetch, per chain.
    float eA0 = fbA[(size_t)1 * kT], eA1 = fbA[(size_t)2 * kT],
          eA2 = fbA[(size_t)3 * kT], eA3 = fbA[(size_t)4 * kT];
    float eB0 = fbB[(size_t)1 * kT], eB1 = fbB[(size_t)2 * kT],
          eB2 = fbB[(size_t)3 * kT], eB3 = fbB[(size_t)4 * kT];
    int mregA = mbA[lane];   // mask words for steps 0..63 (coalesced)
    int mregB = mbB[lane];

    for (int blk = 0; blk < 16; ++blk) {
        // Uniform 64-step mask bitmasks in SGPR pairs; per-step gate is
        // s_and/s_lshr + s_cbranch -- zero memory, zero VALU.
        unsigned long long bitsA = __ballot(mregA != 0);
        unsigned long long bitsB = __ballot(mregB != 0);
        if (blk < 15) {
            mregA = mbA[(blk + 1) * 64 + lane];
            mregB = mbB[(blk + 1) * 64 + lane];
        }
        int t = blk * 64;
        const int tend = t + 64;
        if (blk == 0) { bitsA >>= 1; bitsB >>= 1; t = 1; }  // scan starts at 1

        for (; t < tend; ++t) {
            const float eA = eA0;  eA0 = eA1; eA1 = eA2; eA2 = eA3;
            const float eB = eB0;  eB0 = eB1; eB1 = eB2; eB2 = eB3;
            const int tn = (t + 4 < kS) ? (t + 4) : (kS - 1);
            eA3 = fbA[(size_t)tn * kT];
            eB3 = fbB[(size_t)tn * kT];
            const bool mkA = bitsA & 1ull;
            const bool mkB = bitsB & 1ull;
            const bool any = (bitsA | bitsB) & 1ull;
            bitsA >>= 1;
            bitsB >>= 1;

            if (any) {  // wave-uniform: skip only when BOTH chains masked off
                const float peA = partA - eA;  // off the M-critical path
                const float peB = partB - eB;

                // pass 1 (interleaved A/B): M_j = max_i (T[i,j] + part_i)
                REP12(LOADP2)
                v2 mva0 = {-INFINITY, -INFINITY};
                v2 mva1 = mva0, mva2 = mva0, mva3 = mva0;
                v2 mvb0 = mva0, mvb1 = mva0, mvb2 = mva0, mvb3 = mva0;
                REPQ(PASS1)
                mva0 = __builtin_elementwise_max(mva0, mva1);
                mva2 = __builtin_elementwise_max(mva2, mva3);
                mva0 = __builtin_elementwise_max(mva0, mva2);
                mvb0 = __builtin_elementwise_max(mvb0, mvb1);
                mvb2 = __builtin_elementwise_max(mvb2, mvb3);
                mvb0 = __builtin_elementwise_max(mvb0, mvb2);
                const float MA = fmaxf(mva0.x, mva0.y);
                const float MB = fmaxf(mvb0.x, mvb0.y);

                // lane i publishes exp(part_i - e_i - M_i), per chain
                const float eaA = __expf(peA - MA);
                const float eaB = __expf(peB - MB);
                wave_fence();          // p_sh reads precede ea_sh writes
                ea_shA[lane] = eaA;
                ea_shB[lane] = eaB;
                wave_fence();          // ea_sh writes precede LOADQ reads

                // pass 2 (interleaved A/B): S_j = sum_i exp(T[i,j]) * ea_i
                REP12(LOADQ2)
                v2 sva0 = {0.f, 0.f};
                v2 sva1 = sva0, sva2 = sva0, sva3 = sva0;
                v2 svb0 = sva0, svb1 = sva0, svb2 = sva0, svb3 = sva0;
                REPQ(PASS2)
                sva0 = sva0 + sva1;
                sva2 = sva2 + sva3;
                sva0 = sva0 + sva2;
                svb0 = svb0 + svb1;
                svb2 = svb2 + svb3;
                svb0 = svb0 + svb2;
                const float SA = sva0.x + sva0.y;
                const float SB = svb0.x + svb0.y;

                const float valA = 2.0f * eA + MA + __logf(SA);
                const float valB = 2.0f * eB + MB + __logf(SB);
                partA = mkA ? valA : partA;   // uniform cndmask per chain
                partB = mkB ? valB : partB;
                wave_fence();          // LOADQ reads precede p_sh overwrite
                p_shA[lane] = partA;
                p_shB[lane] = partB;
                wave_fence();          // p_sh writes precede next LOADP
            }
        }
    }

    // Final transition-only step; only end_value[:, T-1] is stored.
    {
        REP12(LOADP2)
        v2 mva0 = {-INFINITY, -INFINITY};
        v2 mva1 = mva0, mva2 = mva0, mva3 = mva0;
        v2 mvb0 = mva0, mvb1 = mva0, mvb2 = mva0, mvb3 = mva0;
        REPQ(PASS1)
        mva0 = __builtin_elementwise_max(mva0, mva1);
        mva2 = __builtin_elementwise_max(mva2, mva3);
        mva0 = __builtin_elementwise_max(mva0, mva2);
        mvb0 = __builtin_elementwise_max(mvb0, mvb1);
        mvb2 = __builtin_elementwise_max(mvb2, mvb3);
        mvb0 = __builtin_elementwise_max(mvb0, mvb2);
        const float MA = fmaxf(mva0.x, mva0.y);
        const float MB = fmaxf(mvb0.x, mvb0.y);
        const float eaA = __expf(partA - MA);   // no emission in final step
        const float eaB = __expf(partB - MB);
        wave_fence();
        ea_shA[lane] = eaA;
        ea_shB[lane] = eaB;
        wave_fence();

        REP12(LOADQ2)
        v2 sva0 = {0.f, 0.f};
        v2 sva1 = sva0, sva2 = sva0, sva3 = sva0;
        v2 svb0 = sva0, svb1 = sva0, svb2 = sva0, svb3 = sva0;
        REPQ(PASS2)
        sva0 = sva0 + sva1;
        sva2 = sva2 + sva3;
        sva0 = sva0 + sva2;
        svb0 = svb0 + svb1;
        svb2 = svb2 + svb3;
        svb0 = svb0 + svb2;
        const float SA = sva0.x + sva0.y;
        const float SB = svb0.x + svb0.y;
        const float valA = MA + __logf(SA);
        const float valB = MB + __logf(SB);
        if (lane == kT - 1) {                 // score[b] = end_value[b,-1]
            out[1 + bA] = valA;
            out[1 + bB] = valB;
        }
    }
}

// out[0] = sum(score). Single wave; no barriers needed.
__global__ __launch_bounds__(64) void sum_scores(
    const float* __restrict__ sc, float* __restrict__ out)
{
    float s = 0.f;
    for (int i = (int)threadIdx.x; i < kB; i += 64) s += sc[i];
#pragma unroll
    for (int off = 32; off > 0; off >>= 1) s += __shfl_down(s, off);
    if (threadIdx.x == 0) out[0] = s;
}

extern "C" void kernel_launch(void* const* d_in, const int* in_sizes, int n_in,
                              void* d_out, int out_size, void* d_ws, size_t ws_size,
                              hipStream_t stream) {
    const float* feats = (const float*)d_in[0];
    const int*   mask  = (const int*)d_in[1];
    const float* trans = (const float*)d_in[2];
    float*       out   = (float*)d_out;

    crf_fwd<<<dim3(kB / 2), dim3(64), 0, stream>>>(feats, mask, trans, out);
    sum_scores<<<dim3(1), dim3(64), 0, stream>>>(out + 1, out);
}

// Round 2
// 576.067 us; speedup vs baseline: 1.2837x; 1.2837x over previous
//
#include <hip/hip_runtime.h>
#include <math.h>

// CRF forward partition scan. B=512, S=1024, T=48.
//
// R12: LDS-free broadcast via v_readlane. R11 post-mortem: pairing two
// chains/wave monetized the stall slack (2x work fit in +10% step time)
// but raised executed steps 717->932 (union of two 70% masks) -> net loss.
// Revised model: per-step chain is dominated by TWO LDS all-gather round
// trips (part -> pass1, ea -> pass2): ~120cyc latency + ~144cyc DS-pipe
// each + lgkm waits, vs only ~250cyc of real VALU issue. Fix: both
// broadcasts are one-VGPR-to-all-lanes -> v_readlane with literal lane
// ids puts each value in an SGPR; VALU consumes SGPR operands directly.
// No DS pipe, no waits, no fences, no LDS block. Back to 512 blocks,
// one chain per wave (mask-skip rate restored to 30%).
//  - T column (48) and EV=exp(T) (48) in registers, shared structure
//    from R11 (that part was fine).
//  - reduction-tree op order identical to R10 -> bit-identical results.

constexpr int kB  = 512;
constexpr int kS  = 1024;
constexpr int kT  = 48;

typedef float v2 __attribute__((ext_vector_type(2)));
struct V2P { v2 lo, hi; };

#define REP12(X) X(0) X(1) X(2) X(3) X(4) X(5) X(6) X(7) X(8) X(9) X(10) X(11)

// X(k, i0, i1): EV pair k covers transition rows i0=2k, i1=2k+1
#define REP24(X) \
  X(0,0,1)    X(1,2,3)    X(2,4,5)    X(3,6,7) \
  X(4,8,9)    X(5,10,11)  X(6,12,13)  X(7,14,15) \
  X(8,16,17)  X(9,18,19)  X(10,20,21) X(11,22,23) \
  X(12,24,25) X(13,26,27) X(14,28,29) X(15,30,31) \
  X(16,32,33) X(17,34,35) X(18,36,37) X(19,38,39) \
  X(20,40,41) X(21,42,43) X(22,44,45) X(23,46,47)

// X(q, evA, evB, a, b): quad q (rows 4q..4q+3), EV pair ids, acc ids
#define REPQ(X) \
  X(0,0,1,0,3)    X(1,2,3,1,2)    X(2,4,5,2,1)    X(3,6,7,3,0) \
  X(4,8,9,0,3)    X(5,10,11,1,2)  X(6,12,13,2,1)  X(7,14,15,3,0) \
  X(8,16,17,0,3)  X(9,18,19,1,2)  X(10,20,21,2,1) X(11,22,23,3,0)

// Transition column j, rows 4q..4q+3, held in registers for the whole kernel.
#define DECL_TQ(q)  float4 TQ##q;
#define INIT_TQ(q)  { TQ##q.x = trans[(4*(q)+0)*kT + j]; \
                      TQ##q.y = trans[(4*(q)+1)*kT + j]; \
                      TQ##q.z = trans[(4*(q)+2)*kT + j]; \
                      TQ##q.w = trans[(4*(q)+3)*kT + j]; }

#define DECL_EV(k,i0,i1)  v2 EV##k;
#define INIT_EV(k,i0,i1)  EV##k = (v2){__expf(trans[(i0)*kT + j]), \
                                       __expf(trans[(i1)*kT + j])};

// Broadcast lane i's float to all lanes via v_readlane (SGPR result).
#define RLF(v, i) \
  __builtin_bit_cast(float, __builtin_amdgcn_readlane(__builtin_bit_cast(int, (v)), (i)))

// All-gather of 'part' / 'ea' (one value per lane) into uniform float4s.
#define BCP(q)  const float4 P##q = make_float4( \
    RLF(part, 4*(q)+0), RLF(part, 4*(q)+1), RLF(part, 4*(q)+2), RLF(part, 4*(q)+3));
#define BCQ(q)  const float4 Q##q = make_float4( \
    RLF(ea, 4*(q)+0), RLF(ea, 4*(q)+1), RLF(ea, 4*(q)+2), RLF(ea, 4*(q)+3));

// pass 1: mv[a] = max(mv[a], T.lo + p.lo); mv[b] = max(mv[b], T.hi + p.hi)
#define PASS1(q,evA,evB,a,b) { \
    const V2P t_ = __builtin_bit_cast(V2P, TQ##q); \
    const V2P p_ = __builtin_bit_cast(V2P, P##q);  \
    mv##a = __builtin_elementwise_max(mv##a, t_.lo + p_.lo); \
    mv##b = __builtin_elementwise_max(mv##b, t_.hi + p_.hi); }

// pass 2: sv[a] += EV[evA] * q.lo; sv[b] += EV[evB] * q.hi   (pk_fma)
#define PASS2(q,evA,evB,a,b) { \
    const V2P q_ = __builtin_bit_cast(V2P, Q##q); \
    sv##a = __builtin_elementwise_fma(EV##evA, q_.lo, sv##a); \
    sv##b = __builtin_elementwise_fma(EV##evB, q_.hi, sv##b); }

__global__ __launch_bounds__(64, 1) void crf_fwd(
    const float* __restrict__ feats,   // [B, S, T] fp32
    const int*   __restrict__ mask,    // [B, S] int32 (bool)
    const float* __restrict__ trans,   // [T, T] fp32
    float*       __restrict__ out)     // [1 + B]; we write out[1+b]
{
    const int b    = blockIdx.x;
    const int lane = threadIdx.x;
    const int j    = (lane < kT) ? lane : (kT - 1);  // clamp idle lanes

    // T column and E column live in registers; no LDS anywhere.
    REP12(DECL_TQ)
    REP12(INIT_TQ)
    REP24(DECL_EV)
    REP24(INIT_EV)

    const float* fb = feats + (size_t)b * kS * kT + j;  // lane-offset base
    const int*   mb = mask  + (size_t)b * kS;

    // part0 = emit[0] + transition[T-2, :]   (row 46, column j)
    float part = fb[0] + trans[(kT - 2) * kT + j];

    // Depth-4 register-rotated prefetch of emission only (mask is SALU).
    float e0v = fb[(size_t)1 * kT], e1v = fb[(size_t)2 * kT],
          e2v = fb[(size_t)3 * kT], e3v = fb[(size_t)4 * kT];
    int mreg = mb[lane];   // mask words for steps 0..63 (coalesced)

    for (int blk = 0; blk < 16; ++blk) {
        // Uniform 64-step mask bitmask in an SGPR pair; per-step gate is
        // s_and/s_lshr + s_cbranch -- zero memory, zero VALU.
        unsigned long long bits = __ballot(mreg != 0);
        if (blk < 15) mreg = mb[(blk + 1) * 64 + lane];  // next block's word
        int t = blk * 64;
        const int tend = t + 64;
        if (blk == 0) { bits >>= 1; t = 1; }  // scan starts at step 1

        for (; t < tend; ++t) {
            const float e = e0v;
            e0v = e1v; e1v = e2v; e2v = e3v;
            const int tn = (t + 4 < kS) ? (t + 4) : (kS - 1);
            e3v = fb[(size_t)tn * kT];
            const bool mk = bits & 1ull;
            bits >>= 1;

            if (mk) {  // wave-uniform branch: skip masked-out steps
                const float pe = part - e;  // off the M-critical path

                // all-gather part via readlane; pass 1: M_j = max_i(T[i,j]+part_i)
                REP12(BCP)
                v2 mv0 = {-INFINITY, -INFINITY};
                v2 mv1 = mv0, mv2 = mv0, mv3 = mv0;
                REPQ(PASS1)
                mv0 = __builtin_elementwise_max(mv0, mv1);
                mv2 = __builtin_elementwise_max(mv2, mv3);
                mv0 = __builtin_elementwise_max(mv0, mv2);
                const float M = fmaxf(mv0.x, mv0.y);

                // lane i holds ea_i = exp(part_i - e_i - M_i)
                const float ea = __expf(pe - M);

                // all-gather ea via readlane; pass 2: S_j = sum_i exp(T[i,j])*ea_i
                REP12(BCQ)
                v2 sv0 = {0.f, 0.f};
                v2 sv1 = sv0, sv2 = sv0, sv3 = sv0;
                REPQ(PASS2)
                sv0 = sv0 + sv1;
                sv2 = sv2 + sv3;
                sv0 = sv0 + sv2;
                const float Ssum = sv0.x + sv0.y;

                part = 2.0f * e + M + __logf(Ssum);
            }
        }
    }

    // Final transition-only step; only end_value[:, T-1] is stored.
    {
        REP12(BCP)
        v2 mv0 = {-INFINITY, -INFINITY};
        v2 mv1 = mv0, mv2 = mv0, mv3 = mv0;
        REPQ(PASS1)
        mv0 = __builtin_elementwise_max(mv0, mv1);
        mv2 = __builtin_elementwise_max(mv2, mv3);
        mv0 = __builtin_elementwise_max(mv0, mv2);
        const float M = fmaxf(mv0.x, mv0.y);
        const float ea = __expf(part - M);   // no emission in final step

        REP12(BCQ)
        v2 sv0 = {0.f, 0.f};
        v2 sv1 = sv0, sv2 = sv0, sv3 = sv0;
        REPQ(PASS2)
        sv0 = sv0 + sv1;
        sv2 = sv2 + sv3;
        sv0 = sv0 + sv2;
        const float Ssum = sv0.x + sv0.y;
        const float val = M + __logf(Ssum);
        if (lane == kT - 1) out[1 + b] = val;  // score[b] = end_value[b,-1]
    }
}

// out[0] = sum(score). Single wave; no barriers needed.
__global__ __launch_bounds__(64) void sum_scores(
    const float* __restrict__ sc, float* __restrict__ out)
{
    float s = 0.f;
    for (int i = (int)threadIdx.x; i < kB; i += 64) s += sc[i];
#pragma unroll
    for (int off = 32; off > 0; off >>= 1) s += __shfl_down(s, off);
    if (threadIdx.x == 0) out[0] = s;
}

extern "C" void kernel_launch(void* const* d_in, const int* in_sizes, int n_in,
                              void* d_out, int out_size, void* d_ws, size_t ws_size,
                              hipStream_t stream) {
    const float* feats = (const float*)d_in[0];
    const int*   mask  = (const int*)d_in[1];
    const float* trans = (const float*)d_in[2];
    float*       out   = (float*)d_out;

    crf_fwd<<<dim3(kB), dim3(64), 0, stream>>>(feats, mask, trans, out);
    sum_scores<<<dim3(1), dim3(64), 0, stream>>>(out + 1, out);
}

// Round 3
// 542.922 us; speedup vs baseline: 1.3621x; 1.0611x over previous
//
#include <hip/hip_runtime.h>
#include <math.h>

// CRF forward partition scan. B=512, S=1024, T=48.
//
// R13: asymmetric broadcast. R12 post-mortem: readlane all-gather traded
// LDS stall for issue+hazard 1:1 (VALUBusy 14->26%, time flat). The two
// per-step broadcasts want different mechanisms:
//  - pass1 (part -> packed add/max): LDS broadcast, 12 ds_read_b128 land
//    straight in VGPRs for pk ops (no movs). Latency hidden by PREFETCH:
//    part changes only on executed steps, so the gather refreshed at the
//    END of executed step t stays valid across masked steps and is ready
//    at the next executed step's pass1.
//  - pass2 (ea -> dot product): 48 v_readlane + 48 SCALAR v_fma_f32 with
//    the ea SGPR as one source (1 SGPR/instr legal) -- no movs, no LDS
//    round trip. Accumulator lane-pairing + merge tree bit-identical to
//    the pk_fma version.
// T column (48) + EV=exp(T) (48) stay in registers (proven R11/R12).
// LDS shrinks to p_sh[64] only; ea_sh and 2 fences deleted.

constexpr int kB  = 512;
constexpr int kS  = 1024;
constexpr int kT  = 48;

typedef float v2 __attribute__((ext_vector_type(2)));
struct V2P { v2 lo, hi; };

#define REP12(X) X(0) X(1) X(2) X(3) X(4) X(5) X(6) X(7) X(8) X(9) X(10) X(11)

// X(k, i0, i1): EV pair k covers transition rows i0=2k, i1=2k+1
#define REP24(X) \
  X(0,0,1)    X(1,2,3)    X(2,4,5)    X(3,6,7) \
  X(4,8,9)    X(5,10,11)  X(6,12,13)  X(7,14,15) \
  X(8,16,17)  X(9,18,19)  X(10,20,21) X(11,22,23) \
  X(12,24,25) X(13,26,27) X(14,28,29) X(15,30,31) \
  X(16,32,33) X(17,34,35) X(18,36,37) X(19,38,39) \
  X(20,40,41) X(21,42,43) X(22,44,45) X(23,46,47)

// X(q, evA, evB, a, b): quad q (rows 4q..4q+3), EV pair ids, acc ids
#define REPQ(X) \
  X(0,0,1,0,3)    X(1,2,3,1,2)    X(2,4,5,2,1)    X(3,6,7,3,0) \
  X(4,8,9,0,3)    X(5,10,11,1,2)  X(6,12,13,2,1)  X(7,14,15,3,0) \
  X(8,16,17,0,3)  X(9,18,19,1,2)  X(10,20,21,2,1) X(11,22,23,3,0)

// Transition column j, rows 4q..4q+3, held in registers for the whole kernel.
#define DECL_TQ(q)  float4 TQ##q;
#define INIT_TQ(q)  { TQ##q.x = trans[(4*(q)+0)*kT + j]; \
                      TQ##q.y = trans[(4*(q)+1)*kT + j]; \
                      TQ##q.z = trans[(4*(q)+2)*kT + j]; \
                      TQ##q.w = trans[(4*(q)+3)*kT + j]; }

#define DECL_EV(k,i0,i1)  v2 EV##k;
#define INIT_EV(k,i0,i1)  EV##k = (v2){__expf(trans[(i0)*kT + j]), \
                                       __expf(trans[(i1)*kT + j])};

// Gathered part vector, prefetched into 12 float4 regs (48 VGPRs).
#define DECL_F(q)  float4 F##q;
#define LOADF(q)   F##q = p4[q];

// Broadcast lane i's float to all lanes via v_readlane (SGPR result).
#define RLF(v, i) \
  __builtin_bit_cast(float, __builtin_amdgcn_readlane(__builtin_bit_cast(int, (v)), (i)))

// pass 1 (packed, on prefetched F): mv[a]=max(mv[a],T.lo+p.lo); mv[b] .hi
#define PASS1(q,evA,evB,a,b) { \
    const V2P t_ = __builtin_bit_cast(V2P, TQ##q); \
    const V2P p_ = __builtin_bit_cast(V2P, F##q);  \
    mv##a = __builtin_elementwise_max(mv##a, t_.lo + p_.lo); \
    mv##b = __builtin_elementwise_max(mv##b, t_.hi + p_.hi); }

// pass 2 (scalar fma, ea via readlane SGPR operand). Accumulator mapping
// replicates the pk_fma version exactly: sv[a].x += EV[evA].x * ea[4q+0],
// sv[a].y += EV[evA].y * ea[4q+1], sv[b].x += EV[evB].x * ea[4q+2],
// sv[b].y += EV[evB].y * ea[4q+3]. IEEE fma either way -> bit-identical.
#define PASS2(q,evA,evB,a,b) { \
    const float qx_ = RLF(ea, 4*(q)+0); \
    const float qy_ = RLF(ea, 4*(q)+1); \
    const float qz_ = RLF(ea, 4*(q)+2); \
    const float qw_ = RLF(ea, 4*(q)+3); \
    sv##a##x = fmaf(EV##evA.x, qx_, sv##a##x); \
    sv##a##y = fmaf(EV##evA.y, qy_, sv##a##y); \
    sv##b##x = fmaf(EV##evB.x, qz_, sv##b##x); \
    sv##b##y = fmaf(EV##evB.y, qw_, sv##b##y); }

// Single-wave workgroup: LDS pipe is in-order per wave, so cross-lane RAW
// through LDS needs only a compiler scheduling fence, not s_barrier.
__device__ __forceinline__ void wave_fence() {
    __builtin_amdgcn_wave_barrier();
}

__global__ __launch_bounds__(64, 1) void crf_fwd(
    const float* __restrict__ feats,   // [B, S, T] fp32
    const int*   __restrict__ mask,    // [B, S] int32 (bool)
    const float* __restrict__ trans,   // [T, T] fp32
    float*       __restrict__ out)     // [1 + B]; we write out[1+b]
{
    const int b    = blockIdx.x;
    const int lane = threadIdx.x;
    const int j    = (lane < kT) ? lane : (kT - 1);  // clamp idle lanes

    __shared__ alignas(16) float p_sh[64];
    const float4* p4 = (const float4*)p_sh;

    // T column and E column in registers.
    REP12(DECL_TQ)
    REP12(INIT_TQ)
    REP24(DECL_EV)
    REP24(INIT_EV)
    REP12(DECL_F)

    const float* fb = feats + (size_t)b * kS * kT + j;  // lane-offset base
    const int*   mb = mask  + (size_t)b * kS;

    // part0 = emit[0] + transition[T-2, :]   (row 46, column j)
    float part = fb[0] + trans[(kT - 2) * kT + j];
    p_sh[lane] = part;
    wave_fence();     // order p_sh write before gather reads
    REP12(LOADF)      // prefetch gathered part; valid until next p_sh write

    // Depth-4 register-rotated prefetch of emission only (mask is SALU).
    float e0v = fb[(size_t)1 * kT], e1v = fb[(size_t)2 * kT],
          e2v = fb[(size_t)3 * kT], e3v = fb[(size_t)4 * kT];
    int mreg = mb[lane];   // mask words for steps 0..63 (coalesced)

    for (int blk = 0; blk < 16; ++blk) {
        // Uniform 64-step mask bitmask in an SGPR pair; per-step gate is
        // s_and/s_lshr + s_cbranch -- zero memory, zero VALU.
        unsigned long long bits = __ballot(mreg != 0);
        if (blk < 15) mreg = mb[(blk + 1) * 64 + lane];  // next block's word
        int t = blk * 64;
        const int tend = t + 64;
        if (blk == 0) { bits >>= 1; t = 1; }  // scan starts at step 1

        for (; t < tend; ++t) {
            const float e = e0v;
            e0v = e1v; e1v = e2v; e2v = e3v;
            const int tn = (t + 4 < kS) ? (t + 4) : (kS - 1);
            e3v = fb[(size_t)tn * kT];
            const bool mk = bits & 1ull;
            bits >>= 1;

            if (mk) {  // wave-uniform branch: skip masked-out steps
                const float pe = part - e;  // off the M-critical path

                // pass 1 on prefetched F: M_j = max_i (T[i,j] + part_i)
                v2 mv0 = {-INFINITY, -INFINITY};
                v2 mv1 = mv0, mv2 = mv0, mv3 = mv0;
                REPQ(PASS1)
                mv0 = __builtin_elementwise_max(mv0, mv1);
                mv2 = __builtin_elementwise_max(mv2, mv3);
                mv0 = __builtin_elementwise_max(mv0, mv2);
                const float M = fmaxf(mv0.x, mv0.y);

                // lane i holds ea_i = exp(part_i - e_i - M_i)
                const float ea = __expf(pe - M);

                // pass 2: S_j = sum_i exp(T[i,j]) * ea_i  (readlane + fma)
                float sv0x = 0.f, sv0y = 0.f, sv1x = 0.f, sv1y = 0.f;
                float sv2x = 0.f, sv2y = 0.f, sv3x = 0.f, sv3y = 0.f;
                REPQ(PASS2)
                sv0x += sv1x; sv0y += sv1y;
                sv2x += sv3x; sv2y += sv3y;
                sv0x += sv2x; sv0y += sv2y;
                const float Ssum = sv0x + sv0y;

                part = 2.0f * e + M + __logf(Ssum);

                // publish part and refresh the gather; refreshed F stays
                // valid across masked steps (part unchanged there).
                wave_fence();          // prior F reads precede overwrite
                p_sh[lane] = part;
                wave_fence();          // write precedes gather reads
                REP12(LOADF)
            }
        }
    }

    // Final transition-only step; only end_value[:, T-1] is stored.
    // F regs hold the current gathered part (prefetch invariant).
    {
        v2 mv0 = {-INFINITY, -INFINITY};
        v2 mv1 = mv0, mv2 = mv0, mv3 = mv0;
        REPQ(PASS1)
        mv0 = __builtin_elementwise_max(mv0, mv1);
        mv2 = __builtin_elementwise_max(mv2, mv3);
        mv0 = __builtin_elementwise_max(mv0, mv2);
        const float M = fmaxf(mv0.x, mv0.y);
        const float ea = __expf(part - M);   // no emission in final step

        float sv0x = 0.f, sv0y = 0.f, sv1x = 0.f, sv1y = 0.f;
        float sv2x = 0.f, sv2y = 0.f, sv3x = 0.f, sv3y = 0.f;
        REPQ(PASS2)
        sv0x += sv1x; sv0y += sv1y;
        sv2x += sv3x; sv2y += sv3y;
        sv0x += sv2x; sv0y += sv2y;
        const float Ssum = sv0x + sv0y;
        const float val = M + __logf(Ssum);
        if (lane == kT - 1) out[1 + b] = val;  // score[b] = end_value[b,-1]
    }
}

// out[0] = sum(score). Single wave; no barriers needed.
__global__ __launch_bounds__(64) void sum_scores(
    const float* __restrict__ sc, float* __restrict__ out)
{
    float s = 0.f;
    for (int i = (int)threadIdx.x; i < kB; i += 64) s += sc[i];
#pragma unroll
    for (int off = 32; off > 0; off >>= 1) s += __shfl_down(s, off);
    if (threadIdx.x == 0) out[0] = s;
}

extern "C" void kernel_launch(void* const* d_in, const int* in_sizes, int n_in,
                              void* d_out, int out_size, void* d_ws, size_t ws_size,
                              hipStream_t stream) {
    const float* feats = (const float*)d_in[0];
    const int*   mask  = (const int*)d_in[1];
    const float* trans = (const float*)d_in[2];
    float*       out   = (float*)d_out;

    crf_fwd<<<dim3(kB), dim3(64), 0, stream>>>(feats, mask, trans, out);
    sum_scores<<<dim3(1), dim3(64), 0, stream>>>(out + 1, out);
}

// Round 5
// 433.177 us; speedup vs baseline: 1.7072x; 1.2533x over previous
//
#include <hip/hip_runtime.h>
#include <math.h>

// CRF forward partition scan. B=512, S=1024, T=48.
//
// R14 (resubmit; previous round's failure was container-level infra, not
// the kernel): kill the per-step global emission load. R10/R12/R13 all
// measured ~450-473us despite wildly different broadcast/issue structure
// -> the limiter is shared: the per-step fb[tn*kT] global load. Cycle
// model closes if each iteration waits ~full memory latency (~650 cyc
// avg, feats half-HBM/half-L3 per FETCH_SIZE=50MB) on the freshly issued
// load: 1023*650 + 717*~600 = 1.09M cyc = 455us == measured.
// Fix: stage emissions per 64-step block via global_load_lds (width 16).
// feats rows t0..t0+63 = 12KB CONTIGUOUS = exactly 12 gll calls/wave,
// double-buffered; one (free) vmcnt(0) drain per 64 steps; the inner
// loop has ZERO VMEM ops. e comes from ds_read_b32 whose latency hides
// under pass1 (e first needed at ea, ~300cyc into the step).
// Everything else identical to R13 (TQ/EV/F regs, readlane pass2,
// exact reduction trees -> bit-identical results).

constexpr int kB  = 512;
constexpr int kS  = 1024;
constexpr int kT  = 48;

typedef float v2 __attribute__((ext_vector_type(2)));
struct V2P { v2 lo, hi; };

#define REP12(X) X(0) X(1) X(2) X(3) X(4) X(5) X(6) X(7) X(8) X(9) X(10) X(11)

// X(k, i0, i1): EV pair k covers transition rows i0=2k, i1=2k+1
#define REP24(X) \
  X(0,0,1)    X(1,2,3)    X(2,4,5)    X(3,6,7) \
  X(4,8,9)    X(5,10,11)  X(6,12,13)  X(7,14,15) \
  X(8,16,17)  X(9,18,19)  X(10,20,21) X(11,22,23) \
  X(12,24,25) X(13,26,27) X(14,28,29) X(15,30,31) \
  X(16,32,33) X(17,34,35) X(18,36,37) X(19,38,39) \
  X(20,40,41) X(21,42,43) X(22,44,45) X(23,46,47)

// X(q, evA, evB, a, b): quad q (rows 4q..4q+3), EV pair ids, acc ids
#define REPQ(X) \
  X(0,0,1,0,3)    X(1,2,3,1,2)    X(2,4,5,2,1)    X(3,6,7,3,0) \
  X(4,8,9,0,3)    X(5,10,11,1,2)  X(6,12,13,2,1)  X(7,14,15,3,0) \
  X(8,16,17,0,3)  X(9,18,19,1,2)  X(10,20,21,2,1) X(11,22,23,3,0)

// Transition column j, rows 4q..4q+3, held in registers for the whole kernel.
#define DECL_TQ(q)  float4 TQ##q;
#define INIT_TQ(q)  { TQ##q.x = trans[(4*(q)+0)*kT + j]; \
                      TQ##q.y = trans[(4*(q)+1)*kT + j]; \
                      TQ##q.z = trans[(4*(q)+2)*kT + j]; \
                      TQ##q.w = trans[(4*(q)+3)*kT + j]; }

#define DECL_EV(k,i0,i1)  v2 EV##k;
#define INIT_EV(k,i0,i1)  EV##k = (v2){__expf(trans[(i0)*kT + j]), \
                                       __expf(trans[(i1)*kT + j])};

// Gathered part vector, prefetched into 12 float4 regs (48 VGPRs).
#define DECL_F(q)  float4 F##q;
#define LOADF(q)   F##q = p4[q];

// Broadcast lane i's float to all lanes via v_readlane (SGPR result).
#define RLF(v, i) \
  __builtin_bit_cast(float, __builtin_amdgcn_readlane(__builtin_bit_cast(int, (v)), (i)))

// pass 1 (packed, on prefetched F): mv[a]=max(mv[a],T.lo+p.lo); mv[b] .hi
#define PASS1(q,evA,evB,a,b) { \
    const V2P t_ = __builtin_bit_cast(V2P, TQ##q); \
    const V2P p_ = __builtin_bit_cast(V2P, F##q);  \
    mv##a = __builtin_elementwise_max(mv##a, t_.lo + p_.lo); \
    mv##b = __builtin_elementwise_max(mv##b, t_.hi + p_.hi); }

// pass 2 (scalar fma, ea via readlane SGPR operand). Accumulator mapping
// replicates the pk_fma version exactly -> bit-identical.
#define PASS2(q,evA,evB,a,b) { \
    const float qx_ = RLF(ea, 4*(q)+0); \
    const float qy_ = RLF(ea, 4*(q)+1); \
    const float qz_ = RLF(ea, 4*(q)+2); \
    const float qw_ = RLF(ea, 4*(q)+3); \
    sv##a##x = fmaf(EV##evA.x, qx_, sv##a##x); \
    sv##a##y = fmaf(EV##evA.y, qy_, sv##a##y); \
    sv##b##x = fmaf(EV##evB.x, qz_, sv##b##x); \
    sv##b##y = fmaf(EV##evB.y, qw_, sv##b##y); }

// Single-wave workgroup: LDS pipe is in-order per wave, so cross-lane RAW
// through LDS needs only a compiler scheduling fence, not s_barrier.
__device__ __forceinline__ void wave_fence() {
    __builtin_amdgcn_wave_barrier();
}

__global__ __launch_bounds__(64, 1) void crf_fwd(
    const float* __restrict__ feats,   // [B, S, T] fp32
    const int*   __restrict__ mask,    // [B, S] int32 (bool)
    const float* __restrict__ trans,   // [T, T] fp32
    float*       __restrict__ out)     // [1 + B]; we write out[1+b]
{
    const int b    = blockIdx.x;
    const int lane = threadIdx.x;
    const int j    = (lane < kT) ? lane : (kT - 1);  // clamp idle lanes

    // Emission staging: 64 rows x 48 floats = 12KB per buffer, dbl-buffered.
    __shared__ alignas(16) float e_sh[2][64 * kT];
    __shared__ alignas(16) float p_sh[64];
    const float4* p4 = (const float4*)p_sh;

    const float* fbase = feats + (size_t)b * kS * kT;   // this chain's rows
    const int*   mb    = mask  + (size_t)b * kS;

    // Issue the first 64-row stage EARLY; latency hides under TQ/EV init.
    // 12 calls x (64 lanes x 16B) = 12KB = rows 0..63 (contiguous).
#define STAGE_E(BUFIDX, T0) \
    _Pragma("unroll") \
    for (int c_ = 0; c_ < 12; ++c_) { \
        __builtin_amdgcn_global_load_lds( \
            (const __attribute__((address_space(1))) unsigned int*) \
                (fbase + (size_t)(T0) * kT + c_ * 256 + lane * 4), \
            (__attribute__((address_space(3))) unsigned int*) \
                (&e_sh[BUFIDX][c_ * 256]), \
            16, 0, 0); \
    }

    STAGE_E(0, 0)

    // T column and E column in registers.
    REP12(DECL_TQ)
    REP12(INIT_TQ)
    REP24(DECL_EV)
    REP24(INIT_EV)
    REP12(DECL_F)

    // part0 = emit[0] + transition[T-2, :]   (row 46, column j)
    float part = fbase[j] + trans[(kT - 2) * kT + j];
    p_sh[lane] = part;
    wave_fence();     // order p_sh write before gather reads
    REP12(LOADF)      // prefetch gathered part; valid until next p_sh write

    int mreg = mb[lane];   // mask words for steps 0..63 (coalesced)
    int buf  = 0;

    for (int blk = 0; blk < 16; ++blk) {
        // Drain staging: e_sh[buf] + mreg were issued ~64 steps ago (or at
        // init) -> this wait is effectively free.
        asm volatile("s_waitcnt vmcnt(0)" ::: "memory");

        // Uniform 64-step mask bitmask in an SGPR pair; per-step gate is
        // s_and/s_lshr + s_cbranch -- zero memory, zero VALU.
        unsigned long long bits = __ballot(mreg != 0);
        if (blk < 15) {
            mreg = mb[(blk + 1) * 64 + lane];   // next block's mask word
            STAGE_E(buf ^ 1, (blk + 1) * 64)    // next block's emission rows
        }
        int t = blk * 64;
        const int tend = t + 64;
        if (blk == 0) { bits >>= 1; t = 1; }  // scan starts at step 1

        for (; t < tend; ++t) {
            const bool mk = bits & 1ull;
            bits >>= 1;

            if (mk) {  // wave-uniform branch: skip masked-out steps
                // e from LDS; latency hides under pass1 (first use is ea).
                const float e = e_sh[buf][(t & 63) * kT + j];
                const float pe = part - e;  // off the M-critical path

                // pass 1 on prefetched F: M_j = max_i (T[i,j] + part_i)
                v2 mv0 = {-INFINITY, -INFINITY};
                v2 mv1 = mv0, mv2 = mv0, mv3 = mv0;
                REPQ(PASS1)
                mv0 = __builtin_elementwise_max(mv0, mv1);
                mv2 = __builtin_elementwise_max(mv2, mv3);
                mv0 = __builtin_elementwise_max(mv0, mv2);
                const float M = fmaxf(mv0.x, mv0.y);

                // lane i holds ea_i = exp(part_i - e_i - M_i)
                const float ea = __expf(pe - M);

                // pass 2: S_j = sum_i exp(T[i,j]) * ea_i  (readlane + fma)
                float sv0x = 0.f, sv0y = 0.f, sv1x = 0.f, sv1y = 0.f;
                float sv2x = 0.f, sv2y = 0.f, sv3x = 0.f, sv3y = 0.f;
                REPQ(PASS2)
                sv0x += sv1x; sv0y += sv1y;
                sv2x += sv3x; sv2y += sv3y;
                sv0x += sv2x; sv0y += sv2y;
                const float Ssum = sv0x + sv0y;

                part = 2.0f * e + M + __logf(Ssum);

                // publish part and refresh the gather; refreshed F stays
                // valid across masked steps (part unchanged there).
                wave_fence();          // prior F reads precede overwrite
                p_sh[lane] = part;
                wave_fence();          // write precedes gather reads
                REP12(LOADF)
            }
        }
        buf ^= 1;
    }

    // Final transition-only step; only end_value[:, T-1] is stored.
    // F regs hold the current gathered part (prefetch invariant).
    {
        v2 mv0 = {-INFINITY, -INFINITY};
        v2 mv1 = mv0, mv2 = mv0, mv3 = mv0;
        REPQ(PASS1)
        mv0 = __builtin_elementwise_max(mv0, mv1);
        mv2 = __builtin_elementwise_max(mv2, mv3);
        mv0 = __builtin_elementwise_max(mv0, mv2);
        const float M = fmaxf(mv0.x, mv0.y);
        const float ea = __expf(part - M);   // no emission in final step

        float sv0x = 0.f, sv0y = 0.f, sv1x = 0.f, sv1y = 0.f;
        float sv2x = 0.f, sv2y = 0.f, sv3x = 0.f, sv3y = 0.f;
        REPQ(PASS2)
        sv0x += sv1x; sv0y += sv1y;
        sv2x += sv3x; sv2y += sv3y;
        sv0x += sv2x; sv0y += sv2y;
        const float Ssum = sv0x + sv0y;
        const float val = M + __logf(Ssum);
        if (lane == kT - 1) out[1 + b] = val;  // score[b] = end_value[b,-1]
    }
}

// out[0] = sum(score). Single wave; no barriers needed.
__global__ __launch_bounds__(64) void sum_scores(
    const float* __restrict__ sc, float* __restrict__ out)
{
    float s = 0.f;
    for (int i = (int)threadIdx.x; i < kB; i += 64) s += sc[i];
#pragma unroll
    for (int off = 32; off > 0; off >>= 1) s += __shfl_down(s, off);
    if (threadIdx.x == 0) out[0] = s;
}

extern "C" void kernel_launch(void* const* d_in, const int* in_sizes, int n_in,
                              void* d_out, int out_size, void* d_ws, size_t ws_size,
                              hipStream_t stream) {
    const float* feats = (const float*)d_in[0];
    const int*   mask  = (const int*)d_in[1];
    const float* trans = (const float*)d_in[2];
    float*       out   = (float*)d_out;

    crf_fwd<<<dim3(kB), dim3(64), 0, stream>>>(feats, mask, trans, out);
    sum_scores<<<dim3(1), dim3(64), 0, stream>>>(out + 1, out);
}